// Round 1
// baseline (280.931 us; speedup 1.0000x reference)
//
#include <hip/hip_runtime.h>
#include <stdint.h>
#include <string.h>

// Problem constants (fixed by reference setup_inputs): B=32, C=1, H=384, W=1280
#define NB 32
#define NPIX 491520          // 1*384*1280
#define CHUNKS 48
#define CHUNK (NPIX / CHUNKS) // 10240, divisible by NT*4
#define NT 256
#define BIGF 1e30f

struct Ws {
  double moments[NB][5];   // n, sum_p, sum_g, sum_pp, sum_pg
  double sum_below[NB];    // exact sum of residuals with exp-key < bexp
  float  alpha[NB];
  float  beta[NB];
  int    kk[NB];
  int    bexp[NB];
  int    cbelow[NB];
  int    exphist[NB][256];
  int    subcnt[NB][128];
  float  subsum[NB][128];
};

__device__ __forceinline__ double wave_sum(double v) {
#pragma unroll
  for (int o = 32; o > 0; o >>= 1) v += __shfl_down(v, o, 64);
  return v;
}

// ---------------- K1: masked moments ----------------
__global__ __launch_bounds__(NT) void k_moments(
    const float* __restrict__ pred, const float* __restrict__ gt,
    const int* __restrict__ mask, Ws* __restrict__ ws) {
  const int b = blockIdx.y;
  const size_t base = (size_t)b * NPIX + (size_t)blockIdx.x * CHUNK;
  const float4* p4 = (const float4*)(pred + base);
  const float4* g4 = (const float4*)(gt + base);
  const int4*   m4 = (const int4*)(mask + base);
  double n = 0, sp = 0, sg = 0, spp = 0, spg = 0;
  for (int i = threadIdx.x; i < CHUNK / 4; i += NT) {
    float4 p = p4[i]; float4 g = g4[i]; int4 m = m4[i];
    if (m.x) { n += 1.0; sp += p.x; sg += g.x; spp += (double)(p.x * p.x); spg += (double)(p.x * g.x); }
    if (m.y) { n += 1.0; sp += p.y; sg += g.y; spp += (double)(p.y * p.y); spg += (double)(p.y * g.y); }
    if (m.z) { n += 1.0; sp += p.z; sg += g.z; spp += (double)(p.z * p.z); spg += (double)(p.z * g.z); }
    if (m.w) { n += 1.0; sp += p.w; sg += g.w; spp += (double)(p.w * p.w); spg += (double)(p.w * g.w); }
  }
  n = wave_sum(n); sp = wave_sum(sp); sg = wave_sum(sg);
  spp = wave_sum(spp); spg = wave_sum(spg);
  __shared__ double red[4][5];
  const int lane = threadIdx.x & 63, w = threadIdx.x >> 6;
  if (lane == 0) { red[w][0] = n; red[w][1] = sp; red[w][2] = sg; red[w][3] = spp; red[w][4] = spg; }
  __syncthreads();
  if (threadIdx.x < 5) {
    double s = red[0][threadIdx.x] + red[1][threadIdx.x] + red[2][threadIdx.x] + red[3][threadIdx.x];
    atomicAdd(&ws->moments[b][threadIdx.x], s);
  }
}

// ---------------- K2: per-sample alpha/beta/k ----------------
__global__ void k_coef(Ws* __restrict__ ws) {
  const int b = threadIdx.x;
  if (b >= NB) return;
  const double n = ws->moments[b][0];
  const double ns = n > 1.0 ? n : 1.0;
  const double md = ws->moments[b][1] / ns;
  const double mz = ws->moments[b][2] / ns;
  const double var = ws->moments[b][3] / ns - md * md;
  const double cov = ws->moments[b][4] / ns - md * mz;
  const double a = cov / (var + 1e-6);
  const double be = mz - a * md;
  ws->alpha[b] = (float)a;
  ws->beta[b]  = (float)be;
  ws->kk[b] = (int)floorf(0.8f * (float)n);   // matches jnp.floor((1-0.2)*n) in f32
}

// ---------------- K3: residual + exponent histogram (+ optional residual store) ----------------
__global__ __launch_bounds__(NT) void k_exphist(
    const float* __restrict__ pred, const float* __restrict__ gt,
    const int* __restrict__ mask, Ws* __restrict__ ws,
    float* __restrict__ rout) {
  __shared__ int h[256];
  for (int i = threadIdx.x; i < 256; i += NT) h[i] = 0;
  __syncthreads();
  const int b = blockIdx.y;
  const float a = ws->alpha[b], be = ws->beta[b];
  const size_t base = (size_t)b * NPIX + (size_t)blockIdx.x * CHUNK;
  const float4* p4 = (const float4*)(pred + base);
  const float4* g4 = (const float4*)(gt + base);
  const int4*   m4 = (const int4*)(mask + base);
  float4* r4 = rout ? (float4*)(rout + base) : nullptr;
  for (int i = threadIdx.x; i < CHUNK / 4; i += NT) {
    float4 p = p4[i]; float4 g = g4[i]; int4 m = m4[i];
    float4 r;
    r.x = m.x ? fabsf(a * p.x + be - g.x) : BIGF;
    r.y = m.y ? fabsf(a * p.y + be - g.y) : BIGF;
    r.z = m.z ? fabsf(a * p.z + be - g.z) : BIGF;
    r.w = m.w ? fabsf(a * p.w + be - g.w) : BIGF;
    // masked pixels are NOT binned: k < n guarantees they're never kept,
    // and binning them would funnel 50% of lanes onto one LDS address.
    if (m.x) atomicAdd(&h[(__float_as_uint(r.x) >> 23) & 0xFF], 1);
    if (m.y) atomicAdd(&h[(__float_as_uint(r.y) >> 23) & 0xFF], 1);
    if (m.z) atomicAdd(&h[(__float_as_uint(r.z) >> 23) & 0xFF], 1);
    if (m.w) atomicAdd(&h[(__float_as_uint(r.w) >> 23) & 0xFF], 1);
    if (r4) r4[i] = r;
  }
  __syncthreads();
  for (int i = threadIdx.x; i < 256; i += NT) {
    int c = h[i];
    if (c) atomicAdd(&ws->exphist[b][i], c);
  }
}

// ---------------- K4: find crossing exponent bin ----------------
__global__ void k_findbin(Ws* __restrict__ ws) {
  const int b = threadIdx.x;
  if (b >= NB) return;
  const int k = ws->kk[b];
  int cum = 0, bin = 0;
  for (int i = 0; i < 256; i++) {
    int c = ws->exphist[b][i];
    if (cum + c >= k) { bin = i; break; }
    cum += c;
  }
  ws->bexp[b] = bin;
  ws->cbelow[b] = cum;
}

// ---------------- K5a: sub-pass from stored residuals ----------------
__global__ __launch_bounds__(NT) void k_sub_r(
    const float* __restrict__ rin, Ws* __restrict__ ws) {
  __shared__ int scnt[128];
  __shared__ float ssum[128];
  for (int i = threadIdx.x; i < 128; i += NT) { scnt[i] = 0; ssum[i] = 0.f; }
  __syncthreads();
  const int b = blockIdx.y;
  const int bexp = ws->bexp[b];
  const size_t base = (size_t)b * NPIX + (size_t)blockIdx.x * CHUNK;
  const float4* r4 = (const float4*)(rin + base);
  double local = 0.0;
  for (int i = threadIdx.x; i < CHUNK / 4; i += NT) {
    float4 r = r4[i];
    {
      uint32_t t = __float_as_uint(r.x); int e = t >> 23;
      if (e < bexp) local += r.x;
      else if (e == bexp) { int s = (t >> 16) & 0x7F; atomicAdd(&scnt[s], 1); atomicAdd(&ssum[s], r.x); }
    }
    {
      uint32_t t = __float_as_uint(r.y); int e = t >> 23;
      if (e < bexp) local += r.y;
      else if (e == bexp) { int s = (t >> 16) & 0x7F; atomicAdd(&scnt[s], 1); atomicAdd(&ssum[s], r.y); }
    }
    {
      uint32_t t = __float_as_uint(r.z); int e = t >> 23;
      if (e < bexp) local += r.z;
      else if (e == bexp) { int s = (t >> 16) & 0x7F; atomicAdd(&scnt[s], 1); atomicAdd(&ssum[s], r.z); }
    }
    {
      uint32_t t = __float_as_uint(r.w); int e = t >> 23;
      if (e < bexp) local += r.w;
      else if (e == bexp) { int s = (t >> 16) & 0x7F; atomicAdd(&scnt[s], 1); atomicAdd(&ssum[s], r.w); }
    }
  }
  local = wave_sum(local);
  __shared__ double red[4];
  const int lane = threadIdx.x & 63, w = threadIdx.x >> 6;
  if (lane == 0) red[w] = local;
  __syncthreads();
  if (threadIdx.x == 0) atomicAdd(&ws->sum_below[b], red[0] + red[1] + red[2] + red[3]);
  for (int i = threadIdx.x; i < 128; i += NT) {
    if (scnt[i]) {
      atomicAdd(&ws->subcnt[b][i], scnt[i]);
      atomicAdd(&ws->subsum[b][i], ssum[i]);
    }
  }
}

// ---------------- K5b: sub-pass recomputing residuals (small-ws fallback) ----------------
__global__ __launch_bounds__(NT) void k_sub(
    const float* __restrict__ pred, const float* __restrict__ gt,
    const int* __restrict__ mask, Ws* __restrict__ ws) {
  __shared__ int scnt[128];
  __shared__ float ssum[128];
  for (int i = threadIdx.x; i < 128; i += NT) { scnt[i] = 0; ssum[i] = 0.f; }
  __syncthreads();
  const int b = blockIdx.y;
  const int bexp = ws->bexp[b];
  const float a = ws->alpha[b], be = ws->beta[b];
  const size_t base = (size_t)b * NPIX + (size_t)blockIdx.x * CHUNK;
  const float4* p4 = (const float4*)(pred + base);
  const float4* g4 = (const float4*)(gt + base);
  const int4*   m4 = (const int4*)(mask + base);
  double local = 0.0;
  for (int i = threadIdx.x; i < CHUNK / 4; i += NT) {
    float4 p = p4[i]; float4 g = g4[i]; int4 m = m4[i];
    float rv[4]; int mv[4] = {m.x, m.y, m.z, m.w};
    rv[0] = fabsf(a * p.x + be - g.x);
    rv[1] = fabsf(a * p.y + be - g.y);
    rv[2] = fabsf(a * p.z + be - g.z);
    rv[3] = fabsf(a * p.w + be - g.w);
#pragma unroll
    for (int j = 0; j < 4; j++) {
      if (!mv[j]) continue;
      uint32_t t = __float_as_uint(rv[j]); int e = t >> 23;
      if (e < bexp) local += rv[j];
      else if (e == bexp) { int s = (t >> 16) & 0x7F; atomicAdd(&scnt[s], 1); atomicAdd(&ssum[s], rv[j]); }
    }
  }
  local = wave_sum(local);
  __shared__ double red[4];
  const int lane = threadIdx.x & 63, w = threadIdx.x >> 6;
  if (lane == 0) red[w] = local;
  __syncthreads();
  if (threadIdx.x == 0) atomicAdd(&ws->sum_below[b], red[0] + red[1] + red[2] + red[3]);
  for (int i = threadIdx.x; i < 128; i += NT) {
    if (scnt[i]) {
      atomicAdd(&ws->subcnt[b][i], scnt[i]);
      atomicAdd(&ws->subsum[b][i], ssum[i]);
    }
  }
}

// ---------------- K6: finalize ----------------
__global__ void k_final(Ws* __restrict__ ws, float* __restrict__ out) {
  __shared__ float losses[NB];
  const int b = threadIdx.x;
  if (b < NB) {
    const int k = ws->kk[b];
    float loss = 0.f;
    if (k > 0) {
      double kept = ws->sum_below[b];
      int cum = ws->cbelow[b];
      const int be = ws->bexp[b];
      for (int i = 0; i < 128; i++) {
        int c = ws->subcnt[b][i];
        if (c == 0) continue;
        if (cum + c <= k) {
          kept += (double)ws->subsum[b][i];
          cum += c;
          if (cum == k) break;
        } else {
          // crossing sub-bin: approximate remaining elements at sub-bin midpoint
          // (relative width 2^-8 -> error ~1e-5 on the mean, tolerance 1.1e-2)
          float rep = __uint_as_float(((uint32_t)be << 23) | ((uint32_t)i << 16) | 0x8000u);
          kept += (double)(k - cum) * (double)rep;
          break;
        }
      }
      loss = (float)(kept / (double)k);
    }
    losses[b] = loss;
  }
  __syncthreads();
  if (threadIdx.x == 0) {
    double s = 0.0;
    for (int i = 0; i < NB; i++) s += (double)losses[i];
    out[0] = (float)(s / (double)NB);
  }
}

extern "C" void kernel_launch(void* const* d_in, const int* in_sizes, int n_in,
                              void* d_out, int out_size, void* d_ws, size_t ws_size,
                              hipStream_t stream) {
  const float* pred = (const float*)d_in[0];
  const float* gt   = (const float*)d_in[1];
  const int*   mask = (const int*)d_in[2];
  float* out = (float*)d_out;
  Ws* ws = (Ws*)d_ws;

  const size_t roff = (sizeof(Ws) + 255) & ~(size_t)255;
  const size_t rbytes = (size_t)NB * NPIX * sizeof(float);
  const bool store = ws_size >= roff + rbytes;   // constant across calls -> same work every call
  float* rws = (float*)((char*)d_ws + roff);

  hipMemsetAsync(d_ws, 0, sizeof(Ws), stream);

  dim3 grid(CHUNKS, NB);
  k_moments<<<grid, NT, 0, stream>>>(pred, gt, mask, ws);
  k_coef<<<1, 64, 0, stream>>>(ws);
  if (store) {
    k_exphist<<<grid, NT, 0, stream>>>(pred, gt, mask, ws, rws);
    k_findbin<<<1, 64, 0, stream>>>(ws);
    k_sub_r<<<grid, NT, 0, stream>>>(rws, ws);
  } else {
    k_exphist<<<grid, NT, 0, stream>>>(pred, gt, mask, ws, nullptr);
    k_findbin<<<1, 64, 0, stream>>>(ws);
    k_sub<<<grid, NT, 0, stream>>>(pred, gt, mask, ws);
  }
  k_final<<<1, 64, 0, stream>>>(ws, out);
}

// Round 2
// 269.130 us; speedup vs baseline: 1.0438x; 1.0438x over previous
//
#include <hip/hip_runtime.h>
#include <stdint.h>

// Problem constants (fixed by reference setup_inputs): B=32, C=1, H=384, W=1280
#define NB 32
#define NPIX 491520            // 1*384*1280
#define CHUNKS 60
#define CHUNK 8192             // NPIX / 60
#define NT 256
#define HALF4 (CHUNK / 8)      // 1024 float4s per half (2-way unrolled)

struct Ws {
  double moments[NB][5];       // n, sum_p, sum_g, sum_pp, sum_pg (f64, matches np ref)
  double sum_below[NB];        // sum of key-representatives with exp-bin < bexp
  int    exphist[NB][256];     // valid-pixel counts per exponent bin (key>>7)
  int    subcnt[NB][128];      // counts per 7-bit mantissa sub-bin in crossing exp bin
};

__device__ __forceinline__ double wave_sum_d(double v) {
#pragma unroll
  for (int o = 32; o > 0; o >>= 1) v += __shfl_down(v, o, 64);
  return v;
}

__device__ __forceinline__ double block_sum_d(double v, double* red4) {
  v = wave_sum_d(v);
  const int lane = threadIdx.x & 63, w = threadIdx.x >> 6;
  if (lane == 0) red4[w] = v;
  __syncthreads();
  return red4[0] + red4[1] + red4[2] + red4[3];
}

// round-to-nearest of f32 residual to 16-bit key (sign0 + 8 exp + 7 mant); monotone in r>=0.
__device__ __forceinline__ uint32_t r_to_key(float r) {
  uint32_t t = __float_as_uint(r);
  return (t + 0x7FFFu + ((t >> 16) & 1u)) >> 16;
}

__device__ __forceinline__ void coef_from_moments(const Ws* ws, int b, float* a_out, float* be_out) {
  const double n = ws->moments[b][0];
  const double ns = n > 1.0 ? n : 1.0;
  const double md = ws->moments[b][1] / ns;
  const double mz = ws->moments[b][2] / ns;
  const double var = ws->moments[b][3] / ns - md * md;
  const double cov = ws->moments[b][4] / ns - md * mz;
  const double a = cov / (var + 1e-6);
  *a_out = (float)a;
  *be_out = (float)(mz - a * md);
}

__device__ __forceinline__ int k_from_n(double n) {
  return (int)floorf(0.8f * (float)n);   // matches jnp.floor((1-0.2)*n) in f32
}

// ---------------- K1: masked moments ----------------
__global__ __launch_bounds__(NT, 8) void k_moments(
    const float* __restrict__ pred, const float* __restrict__ gt,
    const int* __restrict__ mask, Ws* __restrict__ ws) {
  const int b = blockIdx.y;
  const size_t base = (size_t)b * NPIX + (size_t)blockIdx.x * CHUNK;
  const float4* p4 = (const float4*)(pred + base);
  const float4* g4 = (const float4*)(gt + base);
  const int4*   m4 = (const int4*)(mask + base);
  float n = 0.f, sp = 0.f, sg = 0.f, spp = 0.f, spg = 0.f;
  for (int i = threadIdx.x; i < HALF4; i += NT) {
    float4 pa = p4[i], pb = p4[i + HALF4];
    float4 ga = g4[i], gb = g4[i + HALF4];
    int4   ma = m4[i], mb = m4[i + HALF4];
    const float pe[8] = {pa.x, pa.y, pa.z, pa.w, pb.x, pb.y, pb.z, pb.w};
    const float ge[8] = {ga.x, ga.y, ga.z, ga.w, gb.x, gb.y, gb.z, gb.w};
    const int   me[8] = {ma.x, ma.y, ma.z, ma.w, mb.x, mb.y, mb.z, mb.w};
#pragma unroll
    for (int j = 0; j < 8; j++) {
      const float mf = me[j] ? 1.f : 0.f;
      const float pm = pe[j] * mf;
      const float gm = ge[j] * mf;
      n += mf; sp += pm; sg += gm;
      spp = fmaf(pe[j], pm, spp);
      spg = fmaf(pe[j], gm, spg);
    }
  }
  __shared__ double red4[4];
  double s;
  s = block_sum_d((double)n, red4);
  if (threadIdx.x == 0) atomicAdd(&ws->moments[b][0], s);
  __syncthreads();
  s = block_sum_d((double)sp, red4);
  if (threadIdx.x == 0) atomicAdd(&ws->moments[b][1], s);
  __syncthreads();
  s = block_sum_d((double)sg, red4);
  if (threadIdx.x == 0) atomicAdd(&ws->moments[b][2], s);
  __syncthreads();
  s = block_sum_d((double)spp, red4);
  if (threadIdx.x == 0) atomicAdd(&ws->moments[b][3], s);
  __syncthreads();
  s = block_sum_d((double)spg, red4);
  if (threadIdx.x == 0) atomicAdd(&ws->moments[b][4], s);
}

// ---------------- K3: residuals -> u16 keys + exponent histogram ----------------
template <bool STORE>
__global__ __launch_bounds__(NT, 8) void k_resid(
    const float* __restrict__ pred, const float* __restrict__ gt,
    const int* __restrict__ mask, Ws* __restrict__ ws,
    uint16_t* __restrict__ keys) {
  __shared__ int h[256];
  if (threadIdx.x < 256) h[threadIdx.x] = 0;
  const int b = blockIdx.y;
  float a, be;
  coef_from_moments(ws, b, &a, &be);
  __syncthreads();
  const size_t base = (size_t)b * NPIX + (size_t)blockIdx.x * CHUNK;
  const float4* p4 = (const float4*)(pred + base);
  const float4* g4 = (const float4*)(gt + base);
  const int4*   m4 = (const int4*)(mask + base);
  ushort4* k4 = (ushort4*)(keys + base);
  for (int i = threadIdx.x; i < HALF4; i += NT) {
    float4 pa = p4[i], pb = p4[i + HALF4];
    float4 ga = g4[i], gb = g4[i + HALF4];
    int4   ma = m4[i], mb = m4[i + HALF4];
    const float pe[8] = {pa.x, pa.y, pa.z, pa.w, pb.x, pb.y, pb.z, pb.w};
    const float ge[8] = {ga.x, ga.y, ga.z, ga.w, gb.x, gb.y, gb.z, gb.w};
    const int   me[8] = {ma.x, ma.y, ma.z, ma.w, mb.x, mb.y, mb.z, mb.w};
    uint32_t kv[8];
#pragma unroll
    for (int j = 0; j < 8; j++) {
      const float r = fabsf(fmaf(a, pe[j], be) - ge[j]);
      uint32_t key = r_to_key(r);
      if (me[j]) {
        atomicAdd(&h[key >> 7], 1);  // masked never binned: k < n => never kept
      } else {
        key = 0xFFFFu;               // past every threshold (>>7 gives 511)
      }
      kv[j] = key;
    }
    if (STORE) {
      ushort4 ka = {(uint16_t)kv[0], (uint16_t)kv[1], (uint16_t)kv[2], (uint16_t)kv[3]};
      ushort4 kb = {(uint16_t)kv[4], (uint16_t)kv[5], (uint16_t)kv[6], (uint16_t)kv[7]};
      k4[i] = ka;
      k4[i + HALF4] = kb;
    }
  }
  __syncthreads();
  if (threadIdx.x < 256) {
    const int c = h[threadIdx.x];
    if (c) atomicAdd(&ws->exphist[b][threadIdx.x], c);
  }
}

// shared epilogue for the selection kernels
__device__ __forceinline__ void select_epilogue(Ws* ws, int b, float local, int* scnt) {
  __shared__ double red4[4];
  const double s = block_sum_d((double)local, red4);
  if (threadIdx.x == 0 && s != 0.0) atomicAdd(&ws->sum_below[b], s);
  __syncthreads();
  if (threadIdx.x < 128) {
    const int c = scnt[threadIdx.x];
    if (c) atomicAdd(&ws->subcnt[b][threadIdx.x], c);
  }
}

__device__ __forceinline__ int find_bexp_lds(const int* hist, int k) {
  int bexp = -1;
  if (k > 0) {
    int cum = 0;
    for (int i = 0; i < 256; i++) {
      const int c = hist[i];
      if (cum + c >= k) { bexp = i; break; }
      cum += c;
    }
  }
  return bexp;
}

// ---------------- K5a: selection over stored keys ----------------
__global__ __launch_bounds__(NT, 8) void k_select(
    const uint16_t* __restrict__ keys, Ws* __restrict__ ws) {
  __shared__ int hist[256];
  __shared__ int scnt[128];
  __shared__ int sh_bexp;
  const int b = blockIdx.y;
  hist[threadIdx.x] = ws->exphist[b][threadIdx.x];
  if (threadIdx.x < 128) scnt[threadIdx.x] = 0;
  __syncthreads();
  if (threadIdx.x == 0) sh_bexp = find_bexp_lds(hist, k_from_n(ws->moments[b][0]));
  __syncthreads();
  const int bexp = sh_bexp;
  float local = 0.f;
  if (bexp >= 0) {
    const size_t base = (size_t)b * NPIX + (size_t)blockIdx.x * CHUNK;
    const ushort4* k4 = (const ushort4*)(keys + base);
    for (int i = threadIdx.x; i < HALF4; i += NT) {
      const ushort4 ka = k4[i], kb = k4[i + HALF4];
      const uint32_t ke[8] = {ka.x, ka.y, ka.z, ka.w, kb.x, kb.y, kb.z, kb.w};
#pragma unroll
      for (int j = 0; j < 8; j++) {
        const int e = (int)(ke[j] >> 7);
        if (e < bexp) local += __uint_as_float(ke[j] << 16);
        else if (e == bexp) atomicAdd(&scnt[ke[j] & 127], 1);
      }
    }
  }
  select_epilogue(ws, b, local, scnt);
}

// ---------------- K5b: fallback selection recomputing residuals ----------------
__global__ __launch_bounds__(NT, 8) void k_select_rc(
    const float* __restrict__ pred, const float* __restrict__ gt,
    const int* __restrict__ mask, Ws* __restrict__ ws) {
  __shared__ int hist[256];
  __shared__ int scnt[128];
  __shared__ int sh_bexp;
  const int b = blockIdx.y;
  hist[threadIdx.x] = ws->exphist[b][threadIdx.x];
  if (threadIdx.x < 128) scnt[threadIdx.x] = 0;
  float a, be;
  coef_from_moments(ws, b, &a, &be);
  __syncthreads();
  if (threadIdx.x == 0) sh_bexp = find_bexp_lds(hist, k_from_n(ws->moments[b][0]));
  __syncthreads();
  const int bexp = sh_bexp;
  float local = 0.f;
  if (bexp >= 0) {
    const size_t base = (size_t)b * NPIX + (size_t)blockIdx.x * CHUNK;
    const float4* p4 = (const float4*)(pred + base);
    const float4* g4 = (const float4*)(gt + base);
    const int4*   m4 = (const int4*)(mask + base);
    for (int i = threadIdx.x; i < HALF4; i += NT) {
      float4 pa = p4[i], pb = p4[i + HALF4];
      float4 ga = g4[i], gb = g4[i + HALF4];
      int4   ma = m4[i], mb = m4[i + HALF4];
      const float pe[8] = {pa.x, pa.y, pa.z, pa.w, pb.x, pb.y, pb.z, pb.w};
      const float ge[8] = {ga.x, ga.y, ga.z, ga.w, gb.x, gb.y, gb.z, gb.w};
      const int   me[8] = {ma.x, ma.y, ma.z, ma.w, mb.x, mb.y, mb.z, mb.w};
#pragma unroll
      for (int j = 0; j < 8; j++) {
        if (!me[j]) continue;
        const float r = fabsf(fmaf(a, pe[j], be) - ge[j]);
        const uint32_t key = r_to_key(r);
        const int e = (int)(key >> 7);
        if (e < bexp) local += __uint_as_float(key << 16);
        else if (e == bexp) atomicAdd(&scnt[key & 127], 1);
      }
    }
  }
  select_epilogue(ws, b, local, scnt);
}

// ---------------- K6: finalize ----------------
__global__ __launch_bounds__(NT) void k_final(Ws* __restrict__ ws, float* __restrict__ out) {
  __shared__ int ldsE[NB * 256];   // 32 KB
  __shared__ int ldsS[NB * 128];   // 16 KB
  __shared__ double losses[NB];
  for (int i = threadIdx.x; i < NB * 256; i += NT) ldsE[i] = ((const int*)ws->exphist)[i];
  for (int i = threadIdx.x; i < NB * 128; i += NT) ldsS[i] = ((const int*)ws->subcnt)[i];
  __syncthreads();
  const int b = threadIdx.x;
  if (b < NB) {
    const int k = k_from_n(ws->moments[b][0]);
    double loss = 0.0;
    if (k > 0) {
      int cum = 0, bexp = 0;
      for (int i = 0; i < 256; i++) {
        const int c = ldsE[b * 256 + i];
        if (cum + c >= k) { bexp = i; break; }
        cum += c;
      }
      double kept = ws->sum_below[b];
      for (int i = 0; i < 128; i++) {
        const int c = ldsS[b * 128 + i];
        if (!c) continue;
        const float rep = __uint_as_float(((uint32_t)((bexp << 7) | i)) << 16);
        if (cum + c <= k) {
          kept += (double)c * (double)rep;
          cum += c;
          if (cum == k) break;
        } else {
          kept += (double)(k - cum) * (double)rep;  // same key => exact representative
          break;
        }
      }
      loss = kept / (double)k;
    }
    losses[b] = loss;
  }
  __syncthreads();
  if (threadIdx.x == 0) {
    double s = 0.0;
    for (int i = 0; i < NB; i++) s += losses[i];
    out[0] = (float)(s / (double)NB);
  }
}

extern "C" void kernel_launch(void* const* d_in, const int* in_sizes, int n_in,
                              void* d_out, int out_size, void* d_ws, size_t ws_size,
                              hipStream_t stream) {
  const float* pred = (const float*)d_in[0];
  const float* gt   = (const float*)d_in[1];
  const int*   mask = (const int*)d_in[2];
  float* out = (float*)d_out;
  Ws* ws = (Ws*)d_ws;

  const size_t koff = (sizeof(Ws) + 255) & ~(size_t)255;
  const size_t kbytes = (size_t)NB * NPIX * sizeof(uint16_t);
  const bool store = ws_size >= koff + kbytes;   // constant across calls
  uint16_t* keys = (uint16_t*)((char*)d_ws + koff);

  hipMemsetAsync(d_ws, 0, sizeof(Ws), stream);

  dim3 grid(CHUNKS, NB);
  k_moments<<<grid, NT, 0, stream>>>(pred, gt, mask, ws);
  if (store) {
    k_resid<true><<<grid, NT, 0, stream>>>(pred, gt, mask, ws, keys);
    k_select<<<grid, NT, 0, stream>>>(keys, ws);
  } else {
    k_resid<false><<<grid, NT, 0, stream>>>(pred, gt, mask, ws, nullptr);
    k_select_rc<<<grid, NT, 0, stream>>>(pred, gt, mask, ws);
  }
  k_final<<<1, NT, 0, stream>>>(ws, out);
}